// Round 4
// baseline (920.413 us; speedup 1.0000x reference)
//
#include <hip/hip_runtime.h>

#define NB 512
#define NL 2048
#define NC 64
#define START_TAG 62
#define STOP_TAG 63

static __device__ __forceinline__ float2 f2(float x, float y) {
    float2 r; r.x = x; r.y = y; return r;
}

__global__ __launch_bounds__(64) void crf_nll_kernel(
    const float* __restrict__ em, const float* __restrict__ T,
    const float* __restrict__ mask, const int* __restrict__ tags,
    float* __restrict__ out)
{
    const int b = blockIdx.x;
    const int lane = threadIdx.x;

    __shared__ float Traw[NC * NC];
    __shared__ alignas(16) float pbuf[2][NC];

    // Stage raw transitions into LDS (coalesced, one row per iteration).
    #pragma unroll
    for (int i = 0; i < NC; ++i) Traw[i * NC + lane] = T[i * NC + lane];
    __syncthreads();

    const float LOG2E = 1.4426950408889634f;
    const float LN2   = 0.6931471805599453f;

    // Lane j holds column j of expT: col2[k] = (e^{T[2k][j]}, e^{T[2k+1][j]})
    float2 col2[32];
    #pragma unroll
    for (int k = 0; k < 32; ++k) {
        col2[k].x = exp2f(LOG2E * Traw[(2 * k) * NC + lane]);
        col2[k].y = exp2f(LOG2E * Traw[(2 * k + 1) * NC + lane]);
    }

    const float* emrow = em + (size_t)b * (NL * NC);
    const float* mrow  = mask + (size_t)b * NL;
    const int*   trow  = tags + (size_t)b * NL;

    // t = 0 init: alpha0 = em0 + T[START, :]  ->  p = 2^(log2e * alpha0)
    float em0 = emrow[lane];
    float pj  = exp2f(LOG2E * (em0 + Traw[START_TAG * NC + lane]));
    int   E   = 0;                 // accumulated power-of-2 exponent (exact)
    int   tag0 = trow[0];
    float score = (lane == tag0) ? (em0 + Traw[START_TAG * NC + lane]) : 0.0f;
    float msum  = mrow[0];
    int   ptag  = tag0;

    // one forward step in the p-domain
    auto step = [&](int parity, float em_c, float m_c, int tg) {
        // exact power-of-2 renorm based on lane 0's value (scalar path)
        unsigned rb = (unsigned)__builtin_amdgcn_readfirstlane((int)__float_as_uint(pj));
        unsigned e8 = (rb >> 23) & 0xFFu;
        if (e8 != 0u) {
            int ex = (int)e8 - 127;
            pj = ldexpf(pj, -ex);
            E += ex;
        }

        float expem = exp2f(LOG2E * em_c);   // off critical path (issued early)

        pbuf[parity][lane] = pj;
        __syncthreads();

        const float4* pb4 = (const float4*)(&pbuf[parity][0]);
        float2 A0 = f2(0.f, 0.f), A1 = f2(0.f, 0.f);
        float2 A2 = f2(0.f, 0.f), A3 = f2(0.f, 0.f);
        #pragma unroll
        for (int ii = 0; ii < 16; ii += 2) {
            float4 pv = pb4[ii];
            A0 += f2(pv.x, pv.y) * col2[2 * ii + 0];
            A1 += f2(pv.z, pv.w) * col2[2 * ii + 1];
            float4 pw = pb4[ii + 1];
            A2 += f2(pw.x, pw.y) * col2[2 * ii + 2];
            A3 += f2(pw.z, pw.w) * col2[2 * ii + 3];
        }
        float2 Sa = A0 + A2;
        float2 Sb = A1 + A3;
        float2 Sc = Sa + Sb;
        float dot = Sc.x + Sc.y;
        float pnew = dot * expem;

        // fused gold-path score: one-hot on lane == tag_t
        float sc = (lane == tg) ? (em_c + Traw[ptag * NC + lane]) : 0.0f;
        score += m_c * sc;
        msum  += m_c;
        ptag   = tg;

        // masked update (mask semantics of the reference `where`)
        pj = (m_c > 0.0f) ? pnew : pj;
    };

    // 8-deep prefetch ring (fully unrolled -> registers)
    float emv[8]; float mv[8]; int tv[8];
    #pragma unroll
    for (int k = 0; k < 8; ++k) {
        int t = 1 + k;
        emv[k] = emrow[t * NC + lane];
        mv[k]  = mrow[t];
        tv[k]  = trow[t];
    }

    int tb = 1;
    for (; tb + 7 <= NL - 1; tb += 8) {
        #pragma unroll
        for (int k = 0; k < 8; ++k) {
            const int tcur = tb + k;
            float em_c = emv[k];
            float m_c  = mv[k];
            int   tg   = tv[k];
            int tnext = tcur + 8;
            if (tnext > NL - 1) tnext = NL - 1;      // clamped (value unused in tail)
            emv[k] = emrow[tnext * NC + lane];
            mv[k]  = mrow[tnext];
            tv[k]  = trow[tnext];
            step(k & 1, em_c, m_c, tg);
        }
    }
    // tail steps (at most 7), direct loads
    for (int tcur = tb; tcur < NL; ++tcur) {
        float em_c = emrow[tcur * NC + lane];
        float m_c  = mrow[tcur];
        int   tg   = trow[tcur];
        step(tcur & 1, em_c, m_c, tg);
    }

    // partition = ln2 * (E + log2( sum_j p_j * e^{T[j,STOP]} ))
    float term = pj * exp2f(LOG2E * Traw[lane * NC + STOP_TAG]);
    #pragma unroll
    for (int off = 32; off > 0; off >>= 1) {
        term  += __shfl_xor(term, off);
        score += __shfl_xor(score, off);
    }

    if (lane == 0) {
        int last = (int)(msum + 0.5f) - 1;
        int ltag = trow[last];
        float sc_total = score + Traw[ltag * NC + STOP_TAG];
        float partition = LN2 * ((float)E + log2f(term));
        atomicAdd(out, (partition - sc_total) * (1.0f / (float)NB));
    }
}

extern "C" void kernel_launch(void* const* d_in, const int* in_sizes, int n_in,
                              void* d_out, int out_size, void* d_ws, size_t ws_size,
                              hipStream_t stream) {
    const float* em   = (const float*)d_in[0];
    const float* T    = (const float*)d_in[1];
    const float* mask = (const float*)d_in[2];
    const int*   tags = (const int*)d_in[3];
    float* out = (float*)d_out;

    hipMemsetAsync(out, 0, sizeof(float), stream);
    crf_nll_kernel<<<dim3(NB), dim3(64), 0, stream>>>(em, T, mask, tags, out);
}

// Round 5
// 826.964 us; speedup vs baseline: 1.1130x; 1.1130x over previous
//
#include <hip/hip_runtime.h>

#define NB 512
#define NL 2048
#define NC 64
#define START_TAG 62
#define STOP_TAG 63

static __device__ __forceinline__ float2 f2(float x, float y) {
    float2 r; r.x = x; r.y = y; return r;
}

__global__ __launch_bounds__(64) void crf_fused(
    const float* __restrict__ em, const float* __restrict__ T,
    const float* __restrict__ mask, const int* __restrict__ tags,
    float* __restrict__ out)
{
    const int bid  = blockIdx.x;
    const int lane = threadIdx.x;
    const float LOG2E = 1.4426950408889634f;
    const float LN2   = 0.6931471805599453f;

    if (bid < NB) {
        // ================= latency-critical partition chain =================
        const int b  = bid;
        const int h  = lane >> 5;      // which i-half this lane reads from LDS
        const int pl = lane ^ 32;      // partner lane / second output column

        __shared__ alignas(16) float pbuf[2][NC];

        // Preload e^T columns `lane` (A) and `lane^32` (B) for rows 32h..32h+31.
        // Loads are row-coalesced across the wave.
        float2 colA2[16], colB2[16];
        #pragma unroll
        for (int k = 0; k < 16; ++k) {
            const int r0 = 32 * h + 2 * k;
            const int r1 = r0 + 1;
            colA2[k].x = exp2f(LOG2E * T[r0 * NC + lane]);
            colA2[k].y = exp2f(LOG2E * T[r1 * NC + lane]);
            colB2[k].x = exp2f(LOG2E * T[r0 * NC + pl]);
            colB2[k].y = exp2f(LOG2E * T[r1 * NC + pl]);
        }
        const float tstop = exp2f(LOG2E * T[lane * NC + STOP_TAG]);  // e^{T[lane,STOP]}

        const float* emrow = em + (size_t)b * (NL * NC);
        const float* mrow  = mask + (size_t)b * NL;

        // t=0 init in p-domain
        float pj = exp2f(LOG2E * (emrow[lane] + T[START_TAG * NC + lane]));
        int   E  = 0;   // exact power-of-2 exponent accumulator (uniform across lanes)

        auto step = [&](int parity, bool renorm, float em_c, float m_c) {
            if (renorm) {
                // lane-0-anchored exact power-of-2 renorm (lane 0 provably > 0)
                unsigned rb = (unsigned)__builtin_amdgcn_readfirstlane((int)__float_as_uint(pj));
                int ex = (int)((rb >> 23) & 0xFFu) - 127;
                pj = ldexpf(pj, -ex);
                E += ex;
            }
            float expem = exp2f(LOG2E * em_c);   // off critical path

            pbuf[parity][lane] = pj;
            asm volatile("s_waitcnt lgkmcnt(0)" ::: "memory");  // single-wave: replaces barrier

            const float4* pb4 = (const float4*)(&pbuf[parity][0]) + 8 * h;
            float2 a0 = f2(0.f, 0.f), a1 = f2(0.f, 0.f);
            float2 b0 = f2(0.f, 0.f), b1 = f2(0.f, 0.f);
            #pragma unroll
            for (int ii = 0; ii < 8; ii += 2) {
                float4 q = pb4[ii];
                a0 += f2(q.x, q.y) * colA2[2 * ii + 0];
                b0 += f2(q.x, q.y) * colB2[2 * ii + 0];
                a0 += f2(q.z, q.w) * colA2[2 * ii + 1];
                b0 += f2(q.z, q.w) * colB2[2 * ii + 1];
                float4 r = pb4[ii + 1];
                a1 += f2(r.x, r.y) * colA2[2 * ii + 2];
                b1 += f2(r.x, r.y) * colB2[2 * ii + 2];
                a1 += f2(r.z, r.w) * colA2[2 * ii + 3];
                b1 += f2(r.z, r.w) * colB2[2 * ii + 3];
            }
            float2 sa2 = a0 + a1;
            float2 sb2 = b0 + b1;
            float sa = sa2.x + sa2.y;            // my half-dot for column `lane`
            float sb = sb2.x + sb2.y;            // my half-dot for column `lane^32`
            float sbp = __shfl_xor(sb, 32);      // partner's other-half for my column
            float pnew = (sa + sbp) * expem;
            pj = (m_c > 0.0f) ? pnew : pj;
        };

        // 8-deep register prefetch ring (fully unrolled -> static indices)
        float emv[8]; float mv[8];
        #pragma unroll
        for (int k = 0; k < 8; ++k) {
            emv[k] = emrow[(1 + k) * NC + lane];
            mv[k]  = mrow[1 + k];
        }

        int tb = 1;
        for (; tb + 7 <= NL - 1; tb += 8) {
            #pragma unroll
            for (int k = 0; k < 8; ++k) {
                float em_c = emv[k], m_c = mv[k];
                int tn = tb + k + 8;
                if (tn > NL - 1) tn = NL - 1;   // clamp; dup loads harmless
                emv[k] = emrow[tn * NC + lane];
                mv[k]  = mrow[tn];
                step(k & 1, (k & 3) == 0, em_c, m_c);
            }
        }
        // tail: t = 2041..2047 already sit in ring slots 0..6
        #pragma unroll
        for (int k = 0; k < 7; ++k) step(k & 1, (k & 3) == 0, emv[k], mv[k]);

        // partition = ln2 * (E + log2( sum_j p_j * e^{T[j,STOP]} ))
        float tsum = pj * tstop;
        #pragma unroll
        for (int off = 32; off > 0; off >>= 1) tsum += __shfl_xor(tsum, off);
        if (lane == 0) {
            float partition = LN2 * ((float)E + log2f(tsum));
            atomicAdd(out, partition * (1.0f / (float)NB));
        }
    } else {
        // ================= embarrassingly-parallel gold-path score =================
        const int b = bid - NB;
        const float* emb = em + (size_t)b * (NL * NC);
        const float* mb  = mask + (size_t)b * NL;
        const int*   tg_ = tags + (size_t)b * NL;

        float s = 0.0f, msum = 0.0f;
        for (int it = 0; it < NL / 64; ++it) {
            int t = it * 64 + lane;
            float m = mb[t];
            msum += m;
            int tg = tg_[t];
            if (t == 0) {
                s += emb[tg] + T[START_TAG * NC + tg];          // unmasked init term
            } else {
                int pt = tg_[t - 1];
                s += m * (emb[t * NC + tg] + T[pt * NC + tg]);  // masked body term
            }
        }
        #pragma unroll
        for (int off = 32; off > 0; off >>= 1) {
            s    += __shfl_xor(s, off);
            msum += __shfl_xor(msum, off);
        }
        if (lane == 0) {
            int last = (int)(msum + 0.5f) - 1;
            int ltag = tg_[last];
            s += T[ltag * NC + STOP_TAG];                        // unmasked stop term
            atomicAdd(out, -s * (1.0f / (float)NB));
        }
    }
}

extern "C" void kernel_launch(void* const* d_in, const int* in_sizes, int n_in,
                              void* d_out, int out_size, void* d_ws, size_t ws_size,
                              hipStream_t stream) {
    const float* em   = (const float*)d_in[0];
    const float* T    = (const float*)d_in[1];
    const float* mask = (const float*)d_in[2];
    const int*   tags = (const int*)d_in[3];
    float* out = (float*)d_out;

    hipMemsetAsync(out, 0, sizeof(float), stream);
    crf_fused<<<dim3(2 * NB), dim3(64), 0, stream>>>(em, T, mask, tags, out);
}

// Round 7
// 784.875 us; speedup vs baseline: 1.1727x; 1.0536x over previous
//
#include <hip/hip_runtime.h>

#define NB 512
#define NL 2048
#define NC 64
#define START_TAG 62
#define STOP_TAG 63

// Butterfly half-gather: after this, v[0..31] holds (bits of) x from all 32
// lanes of the caller's 32-lane half, in a fixed bijective per-lane order.
// Pattern: offsets {0,16} via shfl_xor(16), then DPP row_ror 8/4/2/1 within
// 16-lane rows -> all 16 rotations x both 16-groups of the half.
static __device__ __forceinline__ void gather32(unsigned x, unsigned v[32]) {
    v[0] = x;
    v[1] = (unsigned)__shfl_xor((int)x, 16, 64);
    #pragma unroll
    for (int r = 0; r < 2; ++r)
        v[2 + r] = (unsigned)__builtin_amdgcn_update_dpp(0, (int)v[r], 0x128, 0xF, 0xF, true); // row_ror:8
    #pragma unroll
    for (int r = 0; r < 4; ++r)
        v[4 + r] = (unsigned)__builtin_amdgcn_update_dpp(0, (int)v[r], 0x124, 0xF, 0xF, true); // row_ror:4
    #pragma unroll
    for (int r = 0; r < 8; ++r)
        v[8 + r] = (unsigned)__builtin_amdgcn_update_dpp(0, (int)v[r], 0x122, 0xF, 0xF, true); // row_ror:2
    #pragma unroll
    for (int r = 0; r < 16; ++r)
        v[16 + r] = (unsigned)__builtin_amdgcn_update_dpp(0, (int)v[r], 0x121, 0xF, 0xF, true); // row_ror:1
}

__global__ __launch_bounds__(64) void crf_fused(
    const float* __restrict__ em, const float* __restrict__ T,
    const float* __restrict__ mask, const int* __restrict__ tags,
    float* __restrict__ out)
{
    const int bid  = blockIdx.x;
    const int lane = threadIdx.x;
    const float LOG2E = 1.4426950408889634f;
    const float LN2   = 0.6931471805599453f;

    if (bid < NB) {
        // ============ latency-critical partition chain (no LDS on path) ============
        const int b  = bid;
        const int pl = lane ^ 32;

        __shared__ float Traw[NC * NC];
        #pragma unroll
        for (int i = 0; i < NC; ++i) Traw[i * NC + lane] = T[i * NC + lane];
        __syncthreads();

        // Discover the gather's lane->source-index map by running it on lane ids.
        unsigned idx[32];
        gather32((unsigned)lane, idx);

        // Pre-permuted coefficient registers:
        //   cA[r] = e^{T[idx[r]][lane]}   (own column, own half-rows)
        //   cB[r] = e^{T[idx[r]][lane^32]} (partner column, own half-rows)
        float cA[32], cB[32];
        #pragma unroll
        for (int r = 0; r < 32; ++r) {
            int i = (int)idx[r];
            cA[r] = exp2f(LOG2E * Traw[i * NC + lane]);
            cB[r] = exp2f(LOG2E * Traw[i * NC + pl]);
        }
        const float tstop = exp2f(LOG2E * Traw[lane * NC + STOP_TAG]);

        const float* emrow = em + (size_t)b * (NL * NC);
        const float* mrow  = mask + (size_t)b * NL;

        float pj = exp2f(LOG2E * (emrow[lane] + Traw[START_TAG * NC + lane]));
        int   E  = 0;   // exact power-of-2 exponent accumulator (uniform)

        auto step = [&](bool renorm, float expem, float m_c) {
            int ex = 0;
            if (renorm) {
                // stale (step-entry) lane-0 anchor: SALU work overlaps the gather;
                // correction folded into the expem multiply below.
                unsigned rb = (unsigned)__builtin_amdgcn_readfirstlane((int)__float_as_uint(pj));
                unsigned e8 = (rb >> 23) & 0xFFu;
                if (e8 != 0u) { ex = (int)e8 - 127; E += ex; }
            }
            unsigned v[32];
            gather32(__float_as_uint(pj), v);

            float a0 = 0.f, a1 = 0.f, a2 = 0.f, a3 = 0.f;
            float b0 = 0.f, b1 = 0.f, b2 = 0.f, b3 = 0.f;
            #pragma unroll
            for (int r = 0; r < 32; r += 4) {
                a0 = fmaf(__uint_as_float(v[r + 0]), cA[r + 0], a0);
                a1 = fmaf(__uint_as_float(v[r + 1]), cA[r + 1], a1);
                a2 = fmaf(__uint_as_float(v[r + 2]), cA[r + 2], a2);
                a3 = fmaf(__uint_as_float(v[r + 3]), cA[r + 3], a3);
                b0 = fmaf(__uint_as_float(v[r + 0]), cB[r + 0], b0);
                b1 = fmaf(__uint_as_float(v[r + 1]), cB[r + 1], b1);
                b2 = fmaf(__uint_as_float(v[r + 2]), cB[r + 2], b2);
                b3 = fmaf(__uint_as_float(v[r + 3]), cB[r + 3], b3);
            }
            float sa = (a0 + a1) + (a2 + a3);         // own col, own half
            float sb = (b0 + b1) + (b2 + b3);         // partner col, own half
            float sbp = __shfl_xor(sb, 32, 64);       // my col, other half
            float pnew = (sa + sbp) * ldexpf(expem, -ex);
            pj = (m_c > 0.0f) ? pnew : pj;
        };

        // 8-deep register prefetch ring; exp2f computed at refill (8 steps early)
        float expemv[8]; float mv[8];
        #pragma unroll
        for (int k = 0; k < 8; ++k) {
            expemv[k] = exp2f(LOG2E * emrow[(1 + k) * NC + lane]);
            mv[k]     = mrow[1 + k];
        }

        int tb = 1;
        for (; tb + 7 <= NL - 1; tb += 8) {
            #pragma unroll
            for (int k = 0; k < 8; ++k) {
                float ev = expemv[k], m_c = mv[k];
                int tn = tb + k + 8;
                if (tn > NL - 1) tn = NL - 1;   // clamp; dup harmless
                expemv[k] = exp2f(LOG2E * emrow[tn * NC + lane]);
                mv[k]     = mrow[tn];
                step((k & 3) == 0, ev, m_c);
            }
        }
        // tail: t = 2041..2047 sit in ring slots 0..6
        #pragma unroll
        for (int k = 0; k < 7; ++k) step((k & 3) == 0, expemv[k], mv[k]);

        // partition = ln2 * (E + log2( sum_j p_j * e^{T[j,STOP]} ))
        float tsum = pj * tstop;
        #pragma unroll
        for (int off = 32; off > 0; off >>= 1) tsum += __shfl_xor(tsum, off, 64);
        if (lane == 0) {
            float partition = LN2 * ((float)E + log2f(tsum));
            atomicAdd(out, partition * (1.0f / (float)NB));
        }
    } else {
        // ============ embarrassingly-parallel gold-path score ============
        const int b = bid - NB;
        const float* emb = em + (size_t)b * (NL * NC);
        const float* mb  = mask + (size_t)b * NL;
        const int*   tg_ = tags + (size_t)b * NL;

        float s = 0.0f, msum = 0.0f;
        for (int it = 0; it < NL / 64; ++it) {
            int t = it * 64 + lane;
            float m = mb[t];
            msum += m;
            int tg = tg_[t];
            if (t == 0) {
                s += emb[tg] + T[START_TAG * NC + tg];          // unmasked init term
            } else {
                int pt = tg_[t - 1];
                s += m * (emb[t * NC + tg] + T[pt * NC + tg]);  // masked body term
            }
        }
        #pragma unroll
        for (int off = 32; off > 0; off >>= 1) {
            s    += __shfl_xor(s, off, 64);
            msum += __shfl_xor(msum, off, 64);
        }
        if (lane == 0) {
            int last = (int)(msum + 0.5f) - 1;
            int ltag = tg_[last];
            s += T[ltag * NC + STOP_TAG];                        // unmasked stop term
            atomicAdd(out, -s * (1.0f / (float)NB));
        }
    }
}

extern "C" void kernel_launch(void* const* d_in, const int* in_sizes, int n_in,
                              void* d_out, int out_size, void* d_ws, size_t ws_size,
                              hipStream_t stream) {
    const float* em   = (const float*)d_in[0];
    const float* T    = (const float*)d_in[1];
    const float* mask = (const float*)d_in[2];
    const int*   tags = (const int*)d_in[3];
    float* out = (float*)d_out;

    hipMemsetAsync(out, 0, sizeof(float), stream);
    crf_fused<<<dim3(2 * NB), dim3(64), 0, stream>>>(em, T, mask, tags, out);
}

// Round 8
// 735.299 us; speedup vs baseline: 1.2518x; 1.0674x over previous
//
#include <hip/hip_runtime.h>

#define NB 512
#define NL 2048
#define NC 64
#define START_TAG 62
#define STOP_TAG 63

typedef unsigned ux2 __attribute__((ext_vector_type(2)));

#define HAS_PL16 __has_builtin(__builtin_amdgcn_permlane16_swap)
#define HAS_PL32 __has_builtin(__builtin_amdgcn_permlane32_swap)

// row_ror:n within 16-lane rows (depth-1, all from same source)
#define ROR1(dst, src, n) \
    (dst) = (unsigned)__builtin_amdgcn_update_dpp(0, (int)(src), 0x120 + (n), 0xF, 0xF, true)

static __device__ __forceinline__ float2 pk2(unsigned lo, unsigned hi) {
    float2 r; r.x = __uint_as_float(lo); r.y = __uint_as_float(hi); return r;
}

// Gather this lane's 32-lane half of x into v[0..31] (bijective per-lane order).
// v[0]=own, v[1]=other 16-row (permlane16_swap, select via precomputed s16),
// v[2..16]=ror 1..15 of v[0], v[17..31]=ror 1..15 of v[1].
static __device__ __forceinline__ void gather_half(unsigned x, bool s16, unsigned v[32]) {
    v[0] = x;
#if HAS_PL16
    {
        ux2 r = __builtin_amdgcn_permlane16_swap(x, x, false, false);
        v[1] = s16 ? r[0] : r[1];
    }
#else
    (void)s16;
    v[1] = (unsigned)__shfl_xor((int)x, 16, 64);
#endif
    ROR1(v[2],  x, 1);  ROR1(v[3],  x, 2);  ROR1(v[4],  x, 3);  ROR1(v[5],  x, 4);
    ROR1(v[6],  x, 5);  ROR1(v[7],  x, 6);  ROR1(v[8],  x, 7);  ROR1(v[9],  x, 8);
    ROR1(v[10], x, 9);  ROR1(v[11], x, 10); ROR1(v[12], x, 11); ROR1(v[13], x, 12);
    ROR1(v[14], x, 13); ROR1(v[15], x, 14); ROR1(v[16], x, 15);
    ROR1(v[17], v[1], 1);  ROR1(v[18], v[1], 2);  ROR1(v[19], v[1], 3);  ROR1(v[20], v[1], 4);
    ROR1(v[21], v[1], 5);  ROR1(v[22], v[1], 6);  ROR1(v[23], v[1], 7);  ROR1(v[24], v[1], 8);
    ROR1(v[25], v[1], 9);  ROR1(v[26], v[1], 10); ROR1(v[27], v[1], 11); ROR1(v[28], v[1], 12);
    ROR1(v[29], v[1], 13); ROR1(v[30], v[1], 14); ROR1(v[31], v[1], 15);
}

__global__ __launch_bounds__(64) void crf_fused(
    const float* __restrict__ em, const float* __restrict__ T,
    const float* __restrict__ mask, const int* __restrict__ tags,
    float* __restrict__ out)
{
    const int bid  = blockIdx.x;
    const int lane = threadIdx.x;
    const float LOG2E = 1.4426950408889634f;
    const float LN2   = 0.6931471805599453f;

    if (bid < NB) {
        // ============ latency-critical partition chain (VALU-only cross-lane) ============
        const int b  = bid;
        const int pl = lane ^ 32;

        __shared__ float Traw[NC * NC];
        #pragma unroll
        for (int i = 0; i < NC; ++i) Traw[i * NC + lane] = T[i * NC + lane];
        __syncthreads();

        // Discover swap-output conventions + gather's lane->source map on lane ids.
        bool s16 = false, s32 = false;
        unsigned idv[32];
        {
            unsigned x = (unsigned)lane;
#if HAS_PL16
            {
                ux2 r = __builtin_amdgcn_permlane16_swap(x, x, false, false);
                s16 = ((r[0] >> 4) & 3u) == (((x >> 4) & 3u) ^ 1u);  // r[0] holds 16-row partner?
            }
#endif
#if HAS_PL32
            {
                ux2 q = __builtin_amdgcn_permlane32_swap(x, x, false, false);
                s32 = ((q[0] >> 5) & 1u) == (((x >> 5) & 1u) ^ 1u);  // q[0] holds 32-half partner?
            }
#endif
            gather_half(x, s16, idv);
        }

        // Pre-permuted, pre-paired coefficient registers (float2 for pk-FMA):
        //   cA2[k] = e^{T[idv[2k..2k+1]][lane]}, cB2[k] = e^{T[idv[2k..2k+1]][lane^32]}
        float2 cA2[16], cB2[16];
        #pragma unroll
        for (int k = 0; k < 16; ++k) {
            int i0 = (int)idv[2 * k], i1 = (int)idv[2 * k + 1];
            cA2[k].x = exp2f(LOG2E * Traw[i0 * NC + lane]);
            cA2[k].y = exp2f(LOG2E * Traw[i1 * NC + lane]);
            cB2[k].x = exp2f(LOG2E * Traw[i0 * NC + pl]);
            cB2[k].y = exp2f(LOG2E * Traw[i1 * NC + pl]);
        }
        const float tstop = exp2f(LOG2E * Traw[lane * NC + STOP_TAG]);

        const float* emrow = em + (size_t)b * (NL * NC);
        const float* mrow  = mask + (size_t)b * NL;

        float pj = exp2f(LOG2E * (emrow[lane] + Traw[START_TAG * NC + lane]));
        int   E  = 0;   // exact power-of-2 exponent accumulator (uniform)

        auto step = [&](bool renorm, float expem, float m_c) {
            int ex = 0;
            if (renorm) {
                // stale (step-entry) lane-0 anchor; correction folded into expem
                unsigned rb = (unsigned)__builtin_amdgcn_readfirstlane((int)__float_as_uint(pj));
                unsigned e8 = (rb >> 23) & 0xFFu;
                if (e8 != 0u) { ex = (int)e8 - 127; E += ex; }
            }
            unsigned v_[32];
            gather_half(__float_as_uint(pj), s16, v_);

            float2 a0 = pk2(0, 0), a1 = pk2(0, 0), a2 = pk2(0, 0), a3 = pk2(0, 0);
            float2 b0 = pk2(0, 0), b1 = pk2(0, 0), b2 = pk2(0, 0), b3 = pk2(0, 0);
            #pragma unroll
            for (int k = 0; k < 16; k += 4) {
                float2 p0 = pk2(v_[2 * k + 0], v_[2 * k + 1]);
                float2 p1 = pk2(v_[2 * k + 2], v_[2 * k + 3]);
                float2 p2 = pk2(v_[2 * k + 4], v_[2 * k + 5]);
                float2 p3 = pk2(v_[2 * k + 6], v_[2 * k + 7]);
                a0 = p0 * cA2[k + 0] + a0;  b0 = p0 * cB2[k + 0] + b0;
                a1 = p1 * cA2[k + 1] + a1;  b1 = p1 * cB2[k + 1] + b1;
                a2 = p2 * cA2[k + 2] + a2;  b2 = p2 * cB2[k + 2] + b2;
                a3 = p3 * cA2[k + 3] + a3;  b3 = p3 * cB2[k + 3] + b3;
            }
            float2 sa2 = (a0 + a1) + (a2 + a3);
            float2 sb2 = (b0 + b1) + (b2 + b3);
            float sa = sa2.x + sa2.y;            // own col, own half-rows
            float sb = sb2.x + sb2.y;            // partner col, own half-rows
            unsigned sbb = __float_as_uint(sb);
            float sbp;
#if HAS_PL32
            {
                ux2 q = __builtin_amdgcn_permlane32_swap(sbb, sbb, false, false);
                sbp = __uint_as_float(s32 ? q[0] : q[1]);
            }
#else
            sbp = __shfl_xor(sb, 32, 64);
#endif
            float pnew = (sa + sbp) * ldexpf(expem, -ex);
            pj = (m_c > 0.0f) ? pnew : pj;
        };

        // 8-deep register prefetch ring; exp2f computed at refill (8 steps early)
        float expemv[8]; float mv[8];
        #pragma unroll
        for (int k = 0; k < 8; ++k) {
            expemv[k] = exp2f(LOG2E * emrow[(1 + k) * NC + lane]);
            mv[k]     = mrow[1 + k];
        }

        int tb = 1;
        for (; tb + 7 <= NL - 1; tb += 8) {
            #pragma unroll
            for (int k = 0; k < 8; ++k) {
                float ev = expemv[k], m_c = mv[k];
                int tn = tb + k + 8;
                if (tn > NL - 1) tn = NL - 1;   // clamp; dup harmless
                expemv[k] = exp2f(LOG2E * emrow[tn * NC + lane]);
                mv[k]     = mrow[tn];
                step((k & 3) == 0, ev, m_c);
            }
        }
        // tail: t = 2041..2047 sit in ring slots 0..6
        #pragma unroll
        for (int k = 0; k < 7; ++k) step((k & 3) == 0, expemv[k], mv[k]);

        // partition = ln2 * (E + log2( sum_j p_j * e^{T[j,STOP]} ))
        float tsum = pj * tstop;
        #pragma unroll
        for (int off = 32; off > 0; off >>= 1) tsum += __shfl_xor(tsum, off, 64);
        if (lane == 0) {
            float partition = LN2 * ((float)E + log2f(tsum));
            atomicAdd(out, partition * (1.0f / (float)NB));
        }
    } else {
        // ============ embarrassingly-parallel gold-path score ============
        const int b = bid - NB;
        const float* emb = em + (size_t)b * (NL * NC);
        const float* mb  = mask + (size_t)b * NL;
        const int*   tg_ = tags + (size_t)b * NL;

        float s = 0.0f, msum = 0.0f;
        for (int it = 0; it < NL / 64; ++it) {
            int t = it * 64 + lane;
            float m = mb[t];
            msum += m;
            int tg = tg_[t];
            if (t == 0) {
                s += emb[tg] + T[START_TAG * NC + tg];          // unmasked init term
            } else {
                int pt = tg_[t - 1];
                s += m * (emb[t * NC + tg] + T[pt * NC + tg]);  // masked body term
            }
        }
        #pragma unroll
        for (int off = 32; off > 0; off >>= 1) {
            s    += __shfl_xor(s, off, 64);
            msum += __shfl_xor(msum, off, 64);
        }
        if (lane == 0) {
            int last = (int)(msum + 0.5f) - 1;
            int ltag = tg_[last];
            s += T[ltag * NC + STOP_TAG];                        // unmasked stop term
            atomicAdd(out, -s * (1.0f / (float)NB));
        }
    }
}

extern "C" void kernel_launch(void* const* d_in, const int* in_sizes, int n_in,
                              void* d_out, int out_size, void* d_ws, size_t ws_size,
                              hipStream_t stream) {
    const float* em   = (const float*)d_in[0];
    const float* T    = (const float*)d_in[1];
    const float* mask = (const float*)d_in[2];
    const int*   tags = (const int*)d_in[3];
    float* out = (float*)d_out;

    hipMemsetAsync(out, 0, sizeof(float), stream);
    crf_fused<<<dim3(2 * NB), dim3(64), 0, stream>>>(em, T, mask, tags, out);
}

// Round 12
// 693.488 us; speedup vs baseline: 1.3272x; 1.0603x over previous
//
#include <hip/hip_runtime.h>

#define NB 512
#define NL 2048
#define NC 64
#define START_TAG 62
#define STOP_TAG 63

typedef unsigned ux2 __attribute__((ext_vector_type(2)));

#define HAS_PL16 __has_builtin(__builtin_amdgcn_permlane16_swap)
#define HAS_PL32 __has_builtin(__builtin_amdgcn_permlane32_swap)

// row_ror:n within 16-lane rows (depth-1, all from same source)
#define ROR1(dst, src, n) \
    (dst) = (unsigned)__builtin_amdgcn_update_dpp(0, (int)(src), 0x120 + (n), 0xF, 0xF, true)

static __device__ __forceinline__ float2 pk2(unsigned lo, unsigned hi) {
    float2 r; r.x = __uint_as_float(lo); r.y = __uint_as_float(hi); return r;
}

// Gather this lane's 32-lane half of x into v[0..31] (bijective per-lane order).
// v[0]=own, v[1]=other 16-row (permlane16_swap, select via precomputed s16),
// v[2..16]=ror 1..15 of v[0], v[17..31]=ror 1..15 of v[1].
static __device__ __forceinline__ void gather_half(unsigned x, bool s16, unsigned v[32]) {
    v[0] = x;
#if HAS_PL16
    {
        ux2 r = __builtin_amdgcn_permlane16_swap(x, x, false, false);
        v[1] = s16 ? r[0] : r[1];
    }
#else
    (void)s16;
    v[1] = (unsigned)__shfl_xor((int)x, 16, 64);
#endif
    ROR1(v[2],  x, 1);  ROR1(v[3],  x, 2);  ROR1(v[4],  x, 3);  ROR1(v[5],  x, 4);
    ROR1(v[6],  x, 5);  ROR1(v[7],  x, 6);  ROR1(v[8],  x, 7);  ROR1(v[9],  x, 8);
    ROR1(v[10], x, 9);  ROR1(v[11], x, 10); ROR1(v[12], x, 11); ROR1(v[13], x, 12);
    ROR1(v[14], x, 13); ROR1(v[15], x, 14); ROR1(v[16], x, 15);
    ROR1(v[17], v[1], 1);  ROR1(v[18], v[1], 2);  ROR1(v[19], v[1], 3);  ROR1(v[20], v[1], 4);
    ROR1(v[21], v[1], 5);  ROR1(v[22], v[1], 6);  ROR1(v[23], v[1], 7);  ROR1(v[24], v[1], 8);
    ROR1(v[25], v[1], 9);  ROR1(v[26], v[1], 10); ROR1(v[27], v[1], 11); ROR1(v[28], v[1], 12);
    ROR1(v[29], v[1], 13); ROR1(v[30], v[1], 14); ROR1(v[31], v[1], 15);
}

__global__ __launch_bounds__(64) void crf_fused(
    const float* __restrict__ em, const float* __restrict__ T,
    const float* __restrict__ mask, const int* __restrict__ tags,
    float* __restrict__ out)
{
    const int bid  = blockIdx.x;
    const int lane = threadIdx.x;
    const float LOG2E = 1.4426950408889634f;
    const float LN2   = 0.6931471805599453f;

    if (bid < NB) {
        // ============ latency-critical partition chain (VALU-only cross-lane) ============
        const int b  = bid;
        const int pl = lane ^ 32;

        __shared__ float Traw[NC * NC];
        #pragma unroll
        for (int i = 0; i < NC; ++i) Traw[i * NC + lane] = T[i * NC + lane];
        __syncthreads();

        // Discover swap-output conventions + gather's lane->source map on lane ids.
        bool s16 = false, s32 = false;
        unsigned idv[32];
        {
            unsigned x = (unsigned)lane;
#if HAS_PL16
            {
                ux2 r = __builtin_amdgcn_permlane16_swap(x, x, false, false);
                s16 = ((r[0] >> 4) & 3u) == (((x >> 4) & 3u) ^ 1u);  // r[0] holds 16-row partner?
            }
#endif
#if HAS_PL32
            {
                ux2 q = __builtin_amdgcn_permlane32_swap(x, x, false, false);
                s32 = ((q[0] >> 5) & 1u) == (((x >> 5) & 1u) ^ 1u);  // q[0] holds 32-half partner?
            }
#endif
            gather_half(x, s16, idv);
        }

        // Pre-permuted, pre-paired coefficient registers (float2 for pk-FMA):
        //   cA2[k] = e^{T[idv[2k..2k+1]][lane]}, cB2[k] = e^{T[idv[2k..2k+1]][lane^32]}
        float2 cA2[16], cB2[16];
        #pragma unroll
        for (int k = 0; k < 16; ++k) {
            int i0 = (int)idv[2 * k], i1 = (int)idv[2 * k + 1];
            cA2[k].x = exp2f(LOG2E * Traw[i0 * NC + lane]);
            cA2[k].y = exp2f(LOG2E * Traw[i1 * NC + lane]);
            cB2[k].x = exp2f(LOG2E * Traw[i0 * NC + pl]);
            cB2[k].y = exp2f(LOG2E * Traw[i1 * NC + pl]);
        }
        const float tstop = exp2f(LOG2E * Traw[lane * NC + STOP_TAG]);

        const float* emrow = em + (size_t)b * (NL * NC);
        const float* mrow  = mask + (size_t)b * NL;

        float pj = exp2f(LOG2E * (emrow[lane] + Traw[START_TAG * NC + lane]));
        int   E  = 0;   // exact power-of-2 exponent accumulator (uniform)

        // step consumes a RAW emission value loaded >=8 steps earlier; exp2f here
        // (dep-free vs the pj chain, hidden under the gather+FMA latency).
        auto step = [&](bool renorm, float em_c, float m_c) {
            float expem = exp2f(LOG2E * em_c);
            int ex = 0;
            if (renorm) {
                // stale (step-entry) lane-0 anchor; correction folded into expem
                unsigned rb = (unsigned)__builtin_amdgcn_readfirstlane((int)__float_as_uint(pj));
                unsigned e8 = (rb >> 23) & 0xFFu;
                if (e8 != 0u) { ex = (int)e8 - 127; E += ex; }
            }
            unsigned v_[32];
            gather_half(__float_as_uint(pj), s16, v_);

            float2 a0 = pk2(0, 0), a1 = pk2(0, 0), a2 = pk2(0, 0), a3 = pk2(0, 0);
            float2 b0 = pk2(0, 0), b1 = pk2(0, 0), b2 = pk2(0, 0), b3 = pk2(0, 0);
            #pragma unroll
            for (int k = 0; k < 16; k += 4) {
                float2 p0 = pk2(v_[2 * k + 0], v_[2 * k + 1]);
                float2 p1 = pk2(v_[2 * k + 2], v_[2 * k + 3]);
                float2 p2 = pk2(v_[2 * k + 4], v_[2 * k + 5]);
                float2 p3 = pk2(v_[2 * k + 6], v_[2 * k + 7]);
                a0 = p0 * cA2[k + 0] + a0;  b0 = p0 * cB2[k + 0] + b0;
                a1 = p1 * cA2[k + 1] + a1;  b1 = p1 * cB2[k + 1] + b1;
                a2 = p2 * cA2[k + 2] + a2;  b2 = p2 * cB2[k + 2] + b2;
                a3 = p3 * cA2[k + 3] + a3;  b3 = p3 * cB2[k + 3] + b3;
            }
            float2 sa2 = (a0 + a1) + (a2 + a3);
            float2 sb2 = (b0 + b1) + (b2 + b3);
            float sa = sa2.x + sa2.y;            // own col, own half-rows
            float sb = sb2.x + sb2.y;            // partner col, own half-rows
            unsigned sbb = __float_as_uint(sb);
            float sbp;
#if HAS_PL32
            {
                ux2 q = __builtin_amdgcn_permlane32_swap(sbb, sbb, false, false);
                sbp = __uint_as_float(s32 ? q[0] : q[1]);
            }
#else
            sbp = __shfl_xor(sb, 32, 64);
#endif
            float pnew = (sa + sbp) * ldexpf(expem, -ex);
            pj = (m_c > 0.0f) ? pnew : pj;
        };

        // 8-deep register prefetch ring holding RAW values (no arithmetic at
        // refill -> no waitcnt until consumption 8 steps later).
        float emv[8]; float mv[8];
        #pragma unroll
        for (int k = 0; k < 8; ++k) {
            emv[k] = emrow[(1 + k) * NC + lane];
            mv[k]  = mrow[1 + k];
        }

        int tb = 1;
        for (; tb + 7 <= NL - 1; tb += 8) {
            #pragma unroll
            for (int k = 0; k < 8; ++k) {
                float em_c = emv[k], m_c = mv[k];
                int tn = tb + k + 8;
                if (tn > NL - 1) tn = NL - 1;   // clamp; dup harmless
                emv[k] = emrow[tn * NC + lane];
                mv[k]  = mrow[tn];
                step((k & 3) == 0, em_c, m_c);
            }
        }
        // tail: t = 2041..2047 sit in ring slots 0..6
        #pragma unroll
        for (int k = 0; k < 7; ++k) step((k & 3) == 0, emv[k], mv[k]);

        // partition = ln2 * (E + log2( sum_j p_j * e^{T[j,STOP]} ))
        float tsum = pj * tstop;
        #pragma unroll
        for (int off = 32; off > 0; off >>= 1) tsum += __shfl_xor(tsum, off, 64);
        if (lane == 0) {
            float partition = LN2 * ((float)E + log2f(tsum));
            atomicAdd(out, partition * (1.0f / (float)NB));
        }
    } else {
        // ============ embarrassingly-parallel gold-path score ============
        const int b = bid - NB;
        const float* emb = em + (size_t)b * (NL * NC);
        const float* mb  = mask + (size_t)b * NL;
        const int*   tg_ = tags + (size_t)b * NL;

        float s = 0.0f, msum = 0.0f;
        for (int it = 0; it < NL / 64; ++it) {
            int t = it * 64 + lane;
            float m = mb[t];
            msum += m;
            int tg = tg_[t];
            if (t == 0) {
                s += emb[tg] + T[START_TAG * NC + tg];          // unmasked init term
            } else {
                int pt = tg_[t - 1];
                s += m * (emb[t * NC + tg] + T[pt * NC + tg]);  // masked body term
            }
        }
        #pragma unroll
        for (int off = 32; off > 0; off >>= 1) {
            s    += __shfl_xor(s, off, 64);
            msum += __shfl_xor(msum, off, 64);
        }
        if (lane == 0) {
            int last = (int)(msum + 0.5f) - 1;
            int ltag = tg_[last];
            s += T[ltag * NC + STOP_TAG];                        // unmasked stop term
            atomicAdd(out, -s * (1.0f / (float)NB));
        }
    }
}

extern "C" void kernel_launch(void* const* d_in, const int* in_sizes, int n_in,
                              void* d_out, int out_size, void* d_ws, size_t ws_size,
                              hipStream_t stream) {
    const float* em   = (const float*)d_in[0];
    const float* T    = (const float*)d_in[1];
    const float* mask = (const float*)d_in[2];
    const int*   tags = (const int*)d_in[3];
    float* out = (float*)d_out;

    hipMemsetAsync(out, 0, sizeof(float), stream);
    crf_fused<<<dim3(2 * NB), dim3(64), 0, stream>>>(em, T, mask, tags, out);
}